// Round 1
// baseline (18.210 us; speedup 1.0000x reference)
//
#include <hip/hip_runtime.h>
#include <math.h>

#define PB  64    // blocks per batch for the point kernel
#define TPB 256

// ws layout (floats):
//   [0, B*12)             per-batch M(9 row-major) + t(3)
//   [B*12, B*12 + B*PB)   per-(batch,block) partial sums
//   [B*12 + B*PB]         scalar loss part = 1.5*mean(transLoss) + 2*mean(rotLoss)

__global__ void prep_kernel(const float* __restrict__ predT,
                            const float* __restrict__ target,
                            const float* __restrict__ R_rect,
                            const float* __restrict__ RT,
                            float* __restrict__ ws, int B)
{
    __shared__ float invC[16];
    int tid = threadIdx.x;
    if (tid == 0) {
        // C = R_rect @ RT, then Gauss-Jordan with partial pivoting
        float a[4][8];
        for (int i = 0; i < 4; ++i)
            for (int j = 0; j < 4; ++j) {
                float s = 0.f;
                for (int k = 0; k < 4; ++k) s += R_rect[i*4+k] * RT[k*4+j];
                a[i][j]   = s;
                a[i][j+4] = (i == j) ? 1.f : 0.f;
            }
        for (int col = 0; col < 4; ++col) {
            int p = col; float best = fabsf(a[col][col]);
            for (int r = col+1; r < 4; ++r) {
                float v = fabsf(a[r][col]);
                if (v > best) { best = v; p = r; }
            }
            if (p != col)
                for (int j = 0; j < 8; ++j) { float t = a[col][j]; a[col][j] = a[p][j]; a[p][j] = t; }
            float inv = 1.f / a[col][col];
            for (int j = 0; j < 8; ++j) a[col][j] *= inv;
            for (int r = 0; r < 4; ++r) if (r != col) {
                float f = a[r][col];
                for (int j = 0; j < 8; ++j) a[r][j] -= f * a[col][j];
            }
        }
        for (int i = 0; i < 4; ++i)
            for (int j = 0; j < 4; ++j)
                invC[i*4+j] = a[i][j+4];
    }
    __syncthreads();

    float rl_acc = 0.f, tl_acc = 0.f;
    for (int b = tid; b < B; b += blockDim.x) {
        const float* q = predT + b*7;
        float r = q[0], qi = q[1], qj = q[2], qk = q[3];
        float tx = q[4], ty = q[5], tz = q[6];
        float s = 2.f / (r*r + qi*qi + qj*qj + qk*qk);
        float R[3][3];
        R[0][0] = 1.f - s*(qj*qj + qk*qk); R[0][1] = s*(qi*qj - qk*r);       R[0][2] = s*(qi*qk + qj*r);
        R[1][0] = s*(qi*qj + qk*r);       R[1][1] = 1.f - s*(qi*qi + qk*qk); R[1][2] = s*(qj*qk - qi*r);
        R[2][0] = s*(qi*qk - qj*r);       R[2][1] = s*(qj*qk + qi*r);       R[2][2] = 1.f - s*(qi*qi + qj*qj);

        const float* T = target + b*16;      // row-major 4x4

        // rotationLoss: M = predRot^T @ gtR; ||M - I||_F
        float rl = 0.f;
        for (int i = 0; i < 3; ++i)
            for (int k = 0; k < 3; ++k) {
                float m = R[0][i]*T[0*4+k] + R[1][i]*T[1*4+k] + R[2][i]*T[2*4+k];
                m -= (i == k) ? 1.f : 0.f;
                rl += m*m;
            }
        rl_acc += sqrtf(rl);

        // translationLoss
        float dx = tx - T[3], dy = ty - T[7], dz = tz - T[11];
        tl_acc += sqrtf(dx*dx + dy*dy + dz*dz);

        // D = (target - predSE3) rows 0..2 ; fold invCalib in:
        //   dist(p) = || D[:,:3] @ (invC[:3,:3] p + invC[:3,3]) + D[:,3] ||
        float tr[3] = {tx, ty, tz};
        float D[3][4];
        for (int i = 0; i < 3; ++i) {
            for (int j = 0; j < 3; ++j) D[i][j] = T[i*4+j] - R[i][j];
            D[i][3] = T[i*4+3] - tr[i];
        }
        float* o = ws + b*12;
        for (int i = 0; i < 3; ++i) {
            for (int k = 0; k < 3; ++k)
                o[i*3+k] = D[i][0]*invC[0*4+k] + D[i][1]*invC[1*4+k] + D[i][2]*invC[2*4+k];
            o[9+i]    = D[i][0]*invC[3]     + D[i][1]*invC[7]     + D[i][2]*invC[11]    + D[i][3];
        }
    }
    // one wave (64 threads): butterfly-free shfl_down reduce
    for (int off = 32; off > 0; off >>= 1) {
        rl_acc += __shfl_down(rl_acc, off);
        tl_acc += __shfl_down(tl_acc, off);
    }
    if (tid == 0)
        ws[B*12 + B*PB] = 1.5f * (tl_acc / (float)B) + 2.0f * (rl_acc / (float)B);
}

__global__ __launch_bounds__(TPB) void dist_kernel(
    const float4* __restrict__ pts, const int* __restrict__ sizes,
    const float* __restrict__ ws, float* __restrict__ partials, int N)
{
    int b = blockIdx.y;
    const float* m = ws + b*12;
    float m00=m[0], m01=m[1], m02=m[2];
    float m10=m[3], m11=m[4], m12=m[5];
    float m20=m[6], m21=m[7], m22=m[8];
    float t0=m[9], t1=m[10], t2=m[11];
    int size = sizes[b];                 // only first `size` points contribute
    const float4* p = pts + (size_t)b * N;

    float acc = 0.f;
    for (int n = blockIdx.x * TPB + threadIdx.x; n < size; n += PB * TPB) {
        float4 v = p[n];
        float dx = m00*v.x + m01*v.y + m02*v.z + t0;
        float dy = m10*v.x + m11*v.y + m12*v.z + t1;
        float dz = m20*v.x + m21*v.y + m22*v.z + t2;
        acc += sqrtf(dx*dx + dy*dy + dz*dz);
    }

    __shared__ float sm[TPB/64];
    for (int off = 32; off > 0; off >>= 1) acc += __shfl_down(acc, off);
    if ((threadIdx.x & 63) == 0) sm[threadIdx.x >> 6] = acc;
    __syncthreads();
    if (threadIdx.x == 0) {
        float s = 0.f;
        for (int w = 0; w < TPB/64; ++w) s += sm[w];
        partials[b * PB + blockIdx.x] = s;   // deterministic: fixed slot per block
    }
}

__global__ void final_kernel(const float* __restrict__ partials,
                             const int* __restrict__ sizes,
                             const float* __restrict__ scalar_part,
                             float* __restrict__ out, int B)
{
    int tid = threadIdx.x;
    float acc = 0.f;
    for (int b = tid; b < B; b += 64) {
        float s = 0.f;
        for (int i = 0; i < PB; ++i) s += partials[b*PB + i];
        int sz = sizes[b];
        acc += s / (float)(sz > 1 ? sz : 1);
    }
    for (int off = 32; off > 0; off >>= 1) acc += __shfl_down(acc, off);
    if (tid == 0) {
        float eucl = acc / (float)B;
        out[0] = eucl + scalar_part[0];   // totalLoss
        out[1] = eucl;                    // eucl
    }
}

extern "C" void kernel_launch(void* const* d_in, const int* in_sizes, int n_in,
                              void* d_out, int out_size, void* d_ws, size_t ws_size,
                              hipStream_t stream) {
    const float* predT  = (const float*)d_in[0];
    const float* ptCld  = (const float*)d_in[1];
    const float* target = (const float*)d_in[2];
    const float* R_rect = (const float*)d_in[3];
    const float* RT     = (const float*)d_in[4];
    const int*   sizes  = (const int*)d_in[5];

    int B = in_sizes[0] / 7;
    int N = in_sizes[1] / (B * 4);

    float* ws       = (float*)d_ws;
    float* partials = ws + B*12;
    float* scal     = ws + B*12 + B*PB;
    float* out      = (float*)d_out;

    prep_kernel<<<1, 64, 0, stream>>>(predT, target, R_rect, RT, ws, B);
    dist_kernel<<<dim3(PB, B), TPB, 0, stream>>>((const float4*)ptCld, sizes, ws, partials, N);
    final_kernel<<<1, 64, 0, stream>>>(partials, sizes, scal, out, B);
}